// Round 1
// baseline (479.035 us; speedup 1.0000x reference)
//
#include <hip/hip_runtime.h>
#include <hip/hip_bf16.h>

#define BATCH 4
#define CDIM  256
#define NTOK  4096
#define THREE (3*CDIM)

typedef unsigned short u16;
typedef __attribute__((ext_vector_type(4))) float f32x4;
typedef __attribute__((ext_vector_type(8))) short bf16x8;

__device__ __forceinline__ u16 f2bf(float x) {
  unsigned int u = __float_as_uint(x);
  unsigned int r = (u + 0x7fffu + ((u >> 16) & 1u)) >> 16;   // RTNE
  return (u16)r;
}

// ---------------- K1: weights -> bf16, fg -> additive mask ----------------
__global__ void k_prep(const float* __restrict__ Wqkv, const float* __restrict__ Wproj,
                       const int* __restrict__ fg,
                       u16* __restrict__ wq, u16* __restrict__ wp,
                       float* __restrict__ madd) {
  int i = blockIdx.x * 256 + threadIdx.x;
  const int nq = THREE * CDIM;        // 196608
  const int np = CDIM * CDIM;         // 65536
  const int nm = BATCH * NTOK;        // 16384
  if (i < nq) { wq[i] = f2bf(Wqkv[i]); return; }
  int j = i - nq;
  if (j < np) { wp[j] = f2bf(Wproj[j]); return; }
  int k = j - np;
  if (k < nm) madd[k] = fg[k] ? 0.0f : -1e30f;
}

// ---------------- K2: x [B][C][N] f32 -> xbf [B][N][C] bf16 ----------------
__global__ __launch_bounds__(256) void k_transpose(const float* __restrict__ x, u16* __restrict__ xbf) {
  __shared__ u16 t[64][65];
  int n0 = blockIdx.x * 64;
  int c0 = blockIdx.y * 64;
  int b  = blockIdx.z;
  int tid = threadIdx.x;
  const float* xp = x + (size_t)b * CDIM * NTOK;
  int nl = tid & 63;
  int cb = tid >> 6;
#pragma unroll
  for (int i = 0; i < 16; ++i) {
    int cl = cb * 16 + i;
    t[nl][cl] = f2bf(xp[(size_t)(c0 + cl) * NTOK + n0 + nl]);
  }
  __syncthreads();
  int cl = tid & 63;
  int nb = tid >> 6;
  u16* op = xbf + ((size_t)b * NTOK + n0) * CDIM + c0;
#pragma unroll
  for (int i = 0; i < 16; ++i) {
    int nl2 = nb * 16 + i;
    op[(size_t)nl2 * CDIM + cl] = t[nl2][cl];
  }
}

// ---------------- K3: qkv GEMM. Q (x1/16), K row-major; V transposed [C][N] ----------------
__global__ __launch_bounds__(256) void k_qkv(const u16* __restrict__ xbf, const u16* __restrict__ wq,
                                             u16* __restrict__ Qm, u16* __restrict__ Km,
                                             u16* __restrict__ Vt) {
  __shared__ u16 Al[128][72];
  __shared__ u16 Bl[128][72];
  int n0 = blockIdx.x * 128;
  int d0 = blockIdx.y * 128;
  int b  = blockIdx.z;
  int tid = threadIdx.x;
  int lane = tid & 63, w = tid >> 6;
  int lo = lane & 15, hi = lane >> 4;
  int wm = w >> 1, wn = w & 1;
  f32x4 acc[4][4] = {};
  const u16* Ab = xbf + ((size_t)b * NTOK + n0) * CDIM;
  const u16* Bb = wq + (size_t)d0 * CDIM;
  for (int kc = 0; kc < 256; kc += 64) {
    __syncthreads();
#pragma unroll
    for (int i = 0; i < 4; ++i) {
      int cid = i * 256 + tid;
      int row = cid >> 3, cc = cid & 7;
      *(uint4*)&Al[row][cc * 8] = *(const uint4*)(Ab + (size_t)row * CDIM + kc + cc * 8);
      *(uint4*)&Bl[row][cc * 8] = *(const uint4*)(Bb + (size_t)row * CDIM + kc + cc * 8);
    }
    __syncthreads();
#pragma unroll
    for (int kk = 0; kk < 2; ++kk) {
      bf16x8 af[4], bfr[4];
#pragma unroll
      for (int mi = 0; mi < 4; ++mi) af[mi]  = *(const bf16x8*)&Al[wm * 64 + mi * 16 + lo][kk * 32 + hi * 8];
#pragma unroll
      for (int ni = 0; ni < 4; ++ni) bfr[ni] = *(const bf16x8*)&Bl[wn * 64 + ni * 16 + lo][kk * 32 + hi * 8];
#pragma unroll
      for (int mi = 0; mi < 4; ++mi)
#pragma unroll
        for (int ni = 0; ni < 4; ++ni)
          acc[mi][ni] = __builtin_amdgcn_mfma_f32_16x16x32_bf16(af[mi], bfr[ni], acc[mi][ni], 0, 0, 0);
    }
  }
  int seg = d0 >> 8;   // 0=Q 1=K 2=V (each 128-tile fully inside one segment)
#pragma unroll
  for (int mi = 0; mi < 4; ++mi) {
    int nbase = n0 + wm * 64 + mi * 16 + hi * 4;
#pragma unroll
    for (int ni = 0; ni < 4; ++ni) {
      int d = d0 + wn * 64 + ni * 16 + lo;
      if (seg == 0) {
#pragma unroll
        for (int r = 0; r < 4; ++r)
          Qm[((size_t)b * NTOK + nbase + r) * CDIM + d] = f2bf(acc[mi][ni][r] * 0.0625f);
      } else if (seg == 1) {
        int dk = d - 256;
#pragma unroll
        for (int r = 0; r < 4; ++r)
          Km[((size_t)b * NTOK + nbase + r) * CDIM + dk] = f2bf(acc[mi][ni][r]);
      } else {
        int dv = d - 512;
        ushort4 pk;
        pk.x = f2bf(acc[mi][ni][0]); pk.y = f2bf(acc[mi][ni][1]);
        pk.z = f2bf(acc[mi][ni][2]); pk.w = f2bf(acc[mi][ni][3]);
        *(ushort4*)&Vt[((size_t)b * CDIM + dv) * NTOK + nbase] = pk;
      }
    }
  }
}

// ---------------- K4: flash attention ----------------
// 256 blocks: one (b, 64-row q-tile) each; 4 waves x 16 q-rows; KBLK=64.
__global__ __launch_bounds__(256) void k_attn(const u16* __restrict__ Qm, const u16* __restrict__ Km,
                                              const u16* __restrict__ Vt, const float* __restrict__ madd,
                                              u16* __restrict__ hbuf) {
  __shared__ u16 Kl[64][264];    // keys x C, rows padded +16B (bank step 4)
  __shared__ u16 Vl[256][72];    // C x keys (V already transposed), padded
  __shared__ u16 Pl[4][16][72];  // per-wave P tile, padded
  __shared__ float ml[64];
  int bid = blockIdx.x;
  int xcd = bid & 7;
  int b  = xcd >> 1;                          // 2 XCDs per batch -> K/V L2-resident
  int qt = ((xcd & 1) << 5) | (bid >> 3);     // 0..63
  int tid = threadIdx.x;
  int lane = tid & 63, w = tid >> 6;
  int lo = lane & 15, hi = lane >> 4;
  int n0 = qt * 64 + w * 16;
  // Q fragments in registers (16 rows x 256, 32 VGPRs)
  bf16x8 qf[8];
  const u16* qp = Qm + ((size_t)b * NTOK + n0 + lo) * CDIM + hi * 8;
#pragma unroll
  for (int ks = 0; ks < 8; ++ks) qf[ks] = *(const bf16x8*)(qp + ks * 32);
  f32x4 acc[16] = {};
  float ms[4], ls[4];
#pragma unroll
  for (int r = 0; r < 4; ++r) { ms[r] = -1e30f; ls[r] = 0.0f; }
  const float LOG2E = 1.4426950408889634f;
  const u16* kbase = Km + (size_t)b * NTOK * CDIM;
  const u16* vbase = Vt + (size_t)b * CDIM * NTOK;
  for (int it = 0; it < 64; ++it) {
    int m0 = it * 64;
    __syncthreads();
    // stage K tile: 64 rows x 256 -> 2048 16B chunks
#pragma unroll
    for (int i = 0; i < 8; ++i) {
      int cid = i * 256 + tid;
      int row = cid >> 5, cc = cid & 31;
      *(uint4*)&Kl[row][cc * 8] = *(const uint4*)(kbase + (size_t)(m0 + row) * CDIM + cc * 8);
    }
    // stage Vt tile: 256 rows x 64
#pragma unroll
    for (int i = 0; i < 8; ++i) {
      int cid = i * 256 + tid;
      int row = cid >> 3, cc = cid & 7;
      *(uint4*)&Vl[row][cc * 8] = *(const uint4*)(vbase + (size_t)row * NTOK + m0 + cc * 8);
    }
    if (tid < 64) ml[tid] = madd[(size_t)b * NTOK + m0 + tid];
    __syncthreads();
    // S = Q K^T  (pre-scaled by 1/16 in Q)
    f32x4 s[4] = {};
#pragma unroll
    for (int ks = 0; ks < 8; ++ks) {
#pragma unroll
      for (int ni = 0; ni < 4; ++ni) {
        bf16x8 kf = *(const bf16x8*)&Kl[ni * 16 + lo][ks * 32 + hi * 8];
        s[ni] = __builtin_amdgcn_mfma_f32_16x16x32_bf16(qf[ks], kf, s[ni], 0, 0, 0);
      }
    }
    // mask + online softmax (rows n = hi*4+r live across the 16 lanes sharing hi)
    float p[4][4], tmax[4];
#pragma unroll
    for (int r = 0; r < 4; ++r) tmax[r] = -1e30f;
#pragma unroll
    for (int ni = 0; ni < 4; ++ni) {
      float mv = ml[ni * 16 + lo];
#pragma unroll
      for (int r = 0; r < 4; ++r) {
        float v = s[ni][r] + mv;
        p[ni][r] = v;
        tmax[r] = fmaxf(tmax[r], v);
      }
    }
#pragma unroll
    for (int r = 0; r < 4; ++r) {
      float t = tmax[r];
      t = fmaxf(t, __shfl_xor(t, 1));
      t = fmaxf(t, __shfl_xor(t, 2));
      t = fmaxf(t, __shfl_xor(t, 4));
      t = fmaxf(t, __shfl_xor(t, 8));
      tmax[r] = t;
    }
    float scale[4], rs[4];
#pragma unroll
    for (int r = 0; r < 4; ++r) {
      float mn = fmaxf(ms[r], tmax[r]);
      scale[r] = exp2f((ms[r] - mn) * LOG2E);
      ms[r] = mn;
      rs[r] = 0.0f;
    }
#pragma unroll
    for (int ni = 0; ni < 4; ++ni)
#pragma unroll
      for (int r = 0; r < 4; ++r) {
        float e = exp2f((p[ni][r] - ms[r]) * LOG2E);
        p[ni][r] = e;
        rs[r] += e;
      }
#pragma unroll
    for (int r = 0; r < 4; ++r) {
      float t = rs[r];
      t += __shfl_xor(t, 1); t += __shfl_xor(t, 2);
      t += __shfl_xor(t, 4); t += __shfl_xor(t, 8);
      ls[r] = ls[r] * scale[r] + t;
    }
#pragma unroll
    for (int cf = 0; cf < 16; ++cf) {
      f32x4 a = acc[cf];
#pragma unroll
      for (int r = 0; r < 4; ++r) a[r] *= scale[r];
      acc[cf] = a;
    }
    // P -> bf16 -> per-wave LDS ([n][m] layout for the PV A-fragment)
#pragma unroll
    for (int ni = 0; ni < 4; ++ni)
#pragma unroll
      for (int r = 0; r < 4; ++r)
        Pl[w][hi * 4 + r][ni * 16 + lo] = f2bf(p[ni][r]);
    // PV (DS ops are wave-ordered; Pl is wave-private so no barrier needed)
#pragma unroll
    for (int ks = 0; ks < 2; ++ks) {
      bf16x8 pa = *(const bf16x8*)&Pl[w][lo][ks * 32 + hi * 8];
#pragma unroll
      for (int cf = 0; cf < 16; ++cf) {
        bf16x8 vb = *(const bf16x8*)&Vl[cf * 16 + lo][ks * 32 + hi * 8];
        acc[cf] = __builtin_amdgcn_mfma_f32_16x16x32_bf16(pa, vb, acc[cf], 0, 0, 0);
      }
    }
  }
  // epilogue: h[b][n][c] bf16
  u16* hp = hbuf + ((size_t)b * NTOK + n0) * CDIM;
#pragma unroll
  for (int r = 0; r < 4; ++r) {
    float inv = 1.0f / ls[r];
#pragma unroll
    for (int cf = 0; cf < 16; ++cf)
      hp[(size_t)(hi * 4 + r) * CDIM + cf * 16 + lo] = f2bf(acc[cf][r] * inv);
  }
}

// ---------------- K5: out[b][c][n] = b_proj[c] + sum_k h[b][n][k] Wp[c][k] ----------------
__global__ __launch_bounds__(256) void k_proj(const u16* __restrict__ hbuf, const u16* __restrict__ wp,
                                              const float* __restrict__ bproj, float* __restrict__ out) {
  __shared__ u16 Al[128][72];
  __shared__ u16 Bl[128][72];
  int n0 = blockIdx.x * 128;
  int c0 = blockIdx.y * 128;
  int b  = blockIdx.z;
  int tid = threadIdx.x;
  int lane = tid & 63, w = tid >> 6;
  int lo = lane & 15, hi = lane >> 4;
  int wm = w >> 1, wn = w & 1;
  f32x4 acc[4][4] = {};
  const u16* Ab = wp + (size_t)c0 * CDIM;
  const u16* Bb = hbuf + ((size_t)b * NTOK + n0) * CDIM;
  for (int kc = 0; kc < 256; kc += 64) {
    __syncthreads();
#pragma unroll
    for (int i = 0; i < 4; ++i) {
      int cid = i * 256 + tid;
      int row = cid >> 3, cc = cid & 7;
      *(uint4*)&Al[row][cc * 8] = *(const uint4*)(Ab + (size_t)row * CDIM + kc + cc * 8);
      *(uint4*)&Bl[row][cc * 8] = *(const uint4*)(Bb + (size_t)row * CDIM + kc + cc * 8);
    }
    __syncthreads();
#pragma unroll
    for (int kk = 0; kk < 2; ++kk) {
      bf16x8 af[4], bfr[4];
#pragma unroll
      for (int mi = 0; mi < 4; ++mi) af[mi]  = *(const bf16x8*)&Al[wm * 64 + mi * 16 + lo][kk * 32 + hi * 8];
#pragma unroll
      for (int ni = 0; ni < 4; ++ni) bfr[ni] = *(const bf16x8*)&Bl[wn * 64 + ni * 16 + lo][kk * 32 + hi * 8];
#pragma unroll
      for (int mi = 0; mi < 4; ++mi)
#pragma unroll
        for (int ni = 0; ni < 4; ++ni)
          acc[mi][ni] = __builtin_amdgcn_mfma_f32_16x16x32_bf16(af[mi], bfr[ni], acc[mi][ni], 0, 0, 0);
    }
  }
#pragma unroll
  for (int mi = 0; mi < 4; ++mi) {
    int cbase = c0 + wm * 64 + mi * 16 + hi * 4;
#pragma unroll
    for (int r = 0; r < 4; ++r) {
      float bias = bproj[cbase + r];
#pragma unroll
      for (int ni = 0; ni < 4; ++ni) {
        int n = n0 + wn * 64 + ni * 16 + lo;
        out[((size_t)b * CDIM + cbase + r) * NTOK + n] = acc[mi][ni][r] + bias;
      }
    }
  }
}

extern "C" void kernel_launch(void* const* d_in, const int* in_sizes, int n_in,
                              void* d_out, int out_size, void* d_ws, size_t ws_size,
                              hipStream_t stream) {
  const float* x     = (const float*)d_in[0];
  const int*   fg    = (const int*)d_in[1];
  const float* Wqkv  = (const float*)d_in[2];
  const float* Wproj = (const float*)d_in[3];
  const float* bproj = (const float*)d_in[4];
  float* out = (float*)d_out;
  char* ws = (char*)d_ws;
  // workspace layout (bytes); hbuf reuses xbf (dead after k_qkv). Total ~32.6 MB.
  u16*   xbf  = (u16*)(ws);                    // 8388608  B  (also hbuf)
  u16*   Qm   = (u16*)(ws + 8388608);          // 8388608
  u16*   Km   = (u16*)(ws + 16777216);         // 8388608
  u16*   Vt   = (u16*)(ws + 25165824);         // 8388608
  u16*   wq   = (u16*)(ws + 33554432);         // 393216
  u16*   wp   = (u16*)(ws + 33947648);         // 131072
  float* madd = (float*)(ws + 34078720);       // 65536
  u16*   hbuf = xbf;

  k_prep<<<1088, 256, 0, stream>>>(Wqkv, Wproj, fg, wq, wp, madd);
  k_transpose<<<dim3(64, 4, 4), 256, 0, stream>>>(x, xbf);
  k_qkv<<<dim3(32, 6, 4), 256, 0, stream>>>(xbf, wq, Qm, Km, Vt);
  k_attn<<<256, 256, 0, stream>>>(Qm, Km, Vt, madd, hbuf);
  k_proj<<<dim3(32, 2, 4), 256, 0, stream>>>(hbuf, wp, bproj, out);
}

// Round 2
// 300.690 us; speedup vs baseline: 1.5931x; 1.5931x over previous
//
#include <hip/hip_runtime.h>
#include <hip/hip_bf16.h>

#define BATCH 4
#define CDIM  256
#define NTOK  4096
#define THREE (3*CDIM)

typedef unsigned short u16;
typedef __attribute__((ext_vector_type(4))) float f32x4;
typedef __attribute__((ext_vector_type(8))) short bf16x8;

__device__ __forceinline__ u16 f2bf(float x) {
  unsigned int u = __float_as_uint(x);
  unsigned int r = (u + 0x7fffu + ((u >> 16) & 1u)) >> 16;   // RTNE
  return (u16)r;
}

// ---------------- K1: weights -> bf16, fg -> additive mask ----------------
__global__ void k_prep(const float* __restrict__ Wqkv, const float* __restrict__ Wproj,
                       const int* __restrict__ fg,
                       u16* __restrict__ wq, u16* __restrict__ wp,
                       float* __restrict__ madd) {
  int i = blockIdx.x * 256 + threadIdx.x;
  const int nq = THREE * CDIM;        // 196608
  const int np = CDIM * CDIM;         // 65536
  const int nm = BATCH * NTOK;        // 16384
  if (i < nq) { wq[i] = f2bf(Wqkv[i]); return; }
  int j = i - nq;
  if (j < np) { wp[j] = f2bf(Wproj[j]); return; }
  int k = j - np;
  if (k < nm) madd[k] = fg[k] ? 0.0f : -1e30f;
}

// ---------------- K2: x [B][C][N] f32 -> xbf [B][N][C] bf16 ----------------
__global__ __launch_bounds__(256) void k_transpose(const float* __restrict__ x, u16* __restrict__ xbf) {
  __shared__ u16 t[64][65];
  int n0 = blockIdx.x * 64;
  int c0 = blockIdx.y * 64;
  int b  = blockIdx.z;
  int tid = threadIdx.x;
  const float* xp = x + (size_t)b * CDIM * NTOK;
  int nl = tid & 63;
  int cb = tid >> 6;
#pragma unroll
  for (int i = 0; i < 16; ++i) {
    int cl = cb * 16 + i;
    t[nl][cl] = f2bf(xp[(size_t)(c0 + cl) * NTOK + n0 + nl]);
  }
  __syncthreads();
  int cl = tid & 63;
  int nb = tid >> 6;
  u16* op = xbf + ((size_t)b * NTOK + n0) * CDIM + c0;
#pragma unroll
  for (int i = 0; i < 16; ++i) {
    int nl2 = nb * 16 + i;
    op[(size_t)nl2 * CDIM + cl] = t[nl2][cl];
  }
}

// ---------------- K3: qkv GEMM. Q (x1/16), K row-major; V transposed [C][N] ----------------
__global__ __launch_bounds__(256) void k_qkv(const u16* __restrict__ xbf, const u16* __restrict__ wq,
                                             u16* __restrict__ Qm, u16* __restrict__ Km,
                                             u16* __restrict__ Vt) {
  __shared__ u16 Al[128][72];
  __shared__ u16 Bl[128][72];
  int n0 = blockIdx.x * 128;
  int d0 = blockIdx.y * 128;
  int b  = blockIdx.z;
  int tid = threadIdx.x;
  int lane = tid & 63, w = tid >> 6;
  int lo = lane & 15, hi = lane >> 4;
  int wm = w >> 1, wn = w & 1;
  f32x4 acc[4][4] = {};
  const u16* Ab = xbf + ((size_t)b * NTOK + n0) * CDIM;
  const u16* Bb = wq + (size_t)d0 * CDIM;
  for (int kc = 0; kc < 256; kc += 64) {
    __syncthreads();
#pragma unroll
    for (int i = 0; i < 4; ++i) {
      int cid = i * 256 + tid;
      int row = cid >> 3, cc = cid & 7;
      *(uint4*)&Al[row][cc * 8] = *(const uint4*)(Ab + (size_t)row * CDIM + kc + cc * 8);
      *(uint4*)&Bl[row][cc * 8] = *(const uint4*)(Bb + (size_t)row * CDIM + kc + cc * 8);
    }
    __syncthreads();
#pragma unroll
    for (int kk = 0; kk < 2; ++kk) {
      bf16x8 af[4], bfr[4];
#pragma unroll
      for (int mi = 0; mi < 4; ++mi) af[mi]  = *(const bf16x8*)&Al[wm * 64 + mi * 16 + lo][kk * 32 + hi * 8];
#pragma unroll
      for (int ni = 0; ni < 4; ++ni) bfr[ni] = *(const bf16x8*)&Bl[wn * 64 + ni * 16 + lo][kk * 32 + hi * 8];
#pragma unroll
      for (int mi = 0; mi < 4; ++mi)
#pragma unroll
        for (int ni = 0; ni < 4; ++ni)
          acc[mi][ni] = __builtin_amdgcn_mfma_f32_16x16x32_bf16(af[mi], bfr[ni], acc[mi][ni], 0, 0, 0);
    }
  }
  int seg = d0 >> 8;   // 0=Q 1=K 2=V (each 128-tile fully inside one segment)
#pragma unroll
  for (int mi = 0; mi < 4; ++mi) {
    int nbase = n0 + wm * 64 + mi * 16 + hi * 4;
#pragma unroll
    for (int ni = 0; ni < 4; ++ni) {
      int d = d0 + wn * 64 + ni * 16 + lo;
      if (seg == 0) {
#pragma unroll
        for (int r = 0; r < 4; ++r)
          Qm[((size_t)b * NTOK + nbase + r) * CDIM + d] = f2bf(acc[mi][ni][r] * 0.0625f);
      } else if (seg == 1) {
        int dk = d - 256;
#pragma unroll
        for (int r = 0; r < 4; ++r)
          Km[((size_t)b * NTOK + nbase + r) * CDIM + dk] = f2bf(acc[mi][ni][r]);
      } else {
        int dv = d - 512;
        ushort4 pk;
        pk.x = f2bf(acc[mi][ni][0]); pk.y = f2bf(acc[mi][ni][1]);
        pk.z = f2bf(acc[mi][ni][2]); pk.w = f2bf(acc[mi][ni][3]);
        *(ushort4*)&Vt[((size_t)b * CDIM + dv) * NTOK + nbase] = pk;
      }
    }
  }
}

// ---------------- K4: flash attention, split-K partials ----------------
// grid = 256*nsplit blocks; block = (b, 64-row q-tile, key-chunk s).
// 4 waves x 16 q-rows; KBLK=32; LDS ~42.6KB -> 3 blocks/CU.
__global__ __launch_bounds__(256) void k_attn(const u16* __restrict__ Qm, const u16* __restrict__ Km,
                                              const u16* __restrict__ Vt, const float* __restrict__ madd,
                                              float* __restrict__ pacc, float2* __restrict__ pml,
                                              int lsplit) {
  __shared__ u16 Kl[32][264];    // keys x C, rows padded (+16B)
  __shared__ u16 Vl[256][40];    // C x keys (V pre-transposed), padded
  __shared__ u16 Pl[4][16][40];  // per-wave P tile
  __shared__ float ml[32];
  int nwg = gridDim.x;
  int cpx = nwg >> 3;
  int orig = blockIdx.x;
  int wg = (orig & 7) * cpx + (orig >> 3);   // bijective XCD swizzle (nwg % 8 == 0)
  // wg = (b*nsplit + s)*64 + qt  -> blocks sharing (b,s) are XCD-contiguous
  int qt = wg & 63;
  int bs = wg >> 6;
  int s  = bs & ((1 << lsplit) - 1);
  int b  = bs >> lsplit;
  int chunk = NTOK >> lsplit;
  int koff  = s * chunk;
  int iters = chunk >> 5;
  int g = b * 64 + qt;           // 0..255 (b, qtile) id

  int tid = threadIdx.x;
  int lane = tid & 63, w = tid >> 6;
  int lo = lane & 15, hi = lane >> 4;
  int n0 = qt * 64 + w * 16;
  // Q fragments in registers (16 rows x 256)
  bf16x8 qf[8];
  const u16* qp = Qm + ((size_t)b * NTOK + n0 + lo) * CDIM + hi * 8;
#pragma unroll
  for (int ks = 0; ks < 8; ++ks) qf[ks] = *(const bf16x8*)(qp + ks * 32);
  f32x4 acc[16] = {};
  float ms[4], ls[4];
#pragma unroll
  for (int r = 0; r < 4; ++r) { ms[r] = -1e30f; ls[r] = 0.0f; }
  const float LOG2E = 1.4426950408889634f;
  const u16* kbase = Km + (size_t)b * NTOK * CDIM;
  const u16* vbase = Vt + (size_t)b * CDIM * NTOK;
  for (int it = 0; it < iters; ++it) {
    int m0 = koff + it * 32;
    __syncthreads();
    // stage K tile: 32 rows x 256 -> 1024 16B chunks
#pragma unroll
    for (int i = 0; i < 4; ++i) {
      int cid = i * 256 + tid;
      int row = cid >> 5, cc = cid & 31;
      *(uint4*)&Kl[row][cc * 8] = *(const uint4*)(kbase + (size_t)(m0 + row) * CDIM + cc * 8);
    }
    // stage Vt tile: 256 rows x 32
#pragma unroll
    for (int i = 0; i < 4; ++i) {
      int cid = i * 256 + tid;
      int row = cid >> 2, cc = cid & 3;
      *(uint4*)&Vl[row][cc * 8] = *(const uint4*)(vbase + (size_t)row * NTOK + m0 + cc * 8);
    }
    if (tid < 32) ml[tid] = madd[(size_t)b * NTOK + m0 + tid];
    __syncthreads();
    // S = Q K^T  (pre-scaled by 1/16 in Q)
    f32x4 sv[2] = {};
#pragma unroll
    for (int ks = 0; ks < 8; ++ks) {
#pragma unroll
      for (int ni = 0; ni < 2; ++ni) {
        bf16x8 kf = *(const bf16x8*)&Kl[ni * 16 + lo][ks * 32 + hi * 8];
        sv[ni] = __builtin_amdgcn_mfma_f32_16x16x32_bf16(qf[ks], kf, sv[ni], 0, 0, 0);
      }
    }
    // mask + online softmax (row n = hi*4+r lives across the 16 lanes sharing hi)
    float p[2][4], tmax[4];
#pragma unroll
    for (int r = 0; r < 4; ++r) tmax[r] = -1e30f;
#pragma unroll
    for (int ni = 0; ni < 2; ++ni) {
      float mv = ml[ni * 16 + lo];
#pragma unroll
      for (int r = 0; r < 4; ++r) {
        float v = sv[ni][r] + mv;
        p[ni][r] = v;
        tmax[r] = fmaxf(tmax[r], v);
      }
    }
#pragma unroll
    for (int r = 0; r < 4; ++r) {
      float t = tmax[r];
      t = fmaxf(t, __shfl_xor(t, 1));
      t = fmaxf(t, __shfl_xor(t, 2));
      t = fmaxf(t, __shfl_xor(t, 4));
      t = fmaxf(t, __shfl_xor(t, 8));
      tmax[r] = t;
    }
    float scale[4], rs[4];
#pragma unroll
    for (int r = 0; r < 4; ++r) {
      float mn = fmaxf(ms[r], tmax[r]);
      scale[r] = exp2f((ms[r] - mn) * LOG2E);
      ms[r] = mn;
      rs[r] = 0.0f;
    }
#pragma unroll
    for (int ni = 0; ni < 2; ++ni)
#pragma unroll
      for (int r = 0; r < 4; ++r) {
        float e = exp2f((p[ni][r] - ms[r]) * LOG2E);
        p[ni][r] = e;
        rs[r] += e;
      }
#pragma unroll
    for (int r = 0; r < 4; ++r) {
      float t = rs[r];
      t += __shfl_xor(t, 1); t += __shfl_xor(t, 2);
      t += __shfl_xor(t, 4); t += __shfl_xor(t, 8);
      ls[r] = ls[r] * scale[r] + t;
    }
#pragma unroll
    for (int cf = 0; cf < 16; ++cf) {
      f32x4 a = acc[cf];
#pragma unroll
      for (int r = 0; r < 4; ++r) a[r] *= scale[r];
      acc[cf] = a;
    }
    // P -> bf16 -> per-wave LDS ([n][m] layout for the PV A-fragment)
#pragma unroll
    for (int ni = 0; ni < 2; ++ni)
#pragma unroll
      for (int r = 0; r < 4; ++r)
        Pl[w][hi * 4 + r][ni * 16 + lo] = f2bf(p[ni][r]);
    // PV (DS ops are wave-ordered; Pl is wave-private so no barrier needed)
    {
      bf16x8 pa = *(const bf16x8*)&Pl[w][lo][hi * 8];
#pragma unroll
      for (int cf = 0; cf < 16; ++cf) {
        bf16x8 vb = *(const bf16x8*)&Vl[cf * 16 + lo][hi * 8];
        acc[cf] = __builtin_amdgcn_mfma_f32_16x16x32_bf16(pa, vb, acc[cf], 0, 0, 0);
      }
    }
  }
  // epilogue: unnormalized partial acc + (m,l) per row
  float* pb = pacc + (((size_t)s * 256 + g) * 64 + w * 16) * 256;
#pragma unroll
  for (int r = 0; r < 4; ++r) {
    int row = hi * 4 + r;
#pragma unroll
    for (int cf = 0; cf < 16; ++cf)
      pb[(size_t)row * 256 + cf * 16 + lo] = acc[cf][r];
    if (lo == 0) {
      float2 v; v.x = ms[r]; v.y = ls[r];
      pml[((size_t)s * 256 + g) * 64 + w * 16 + row] = v;
    }
  }
}

// ---------------- K4b: combine split-K partials -> h bf16 ----------------
__global__ __launch_bounds__(256) void k_comb(const float* __restrict__ pacc,
                                              const float2* __restrict__ pml,
                                              u16* __restrict__ hbuf, int nsplit) {
  __shared__ float wgt[4][64];
  const float LOG2E = 1.4426950408889634f;
  int g = blockIdx.x, t = threadIdx.x;
  if (t < 64) {
    float m[4], l[4];
    float M = -3e38f;
#pragma unroll
    for (int s = 0; s < 4; ++s) if (s < nsplit) {
      float2 v = pml[((size_t)s * 256 + g) * 64 + t];
      m[s] = v.x; l[s] = v.y;
      M = fmaxf(M, m[s]);
    }
    float denom = 0.0f;
#pragma unroll
    for (int s = 0; s < 4; ++s) if (s < nsplit) {
      float wv = exp2f((m[s] - M) * LOG2E);
      m[s] = wv;
      denom += l[s] * wv;
    }
    float inv = 1.0f / denom;
#pragma unroll
    for (int s = 0; s < 4; ++s) if (s < nsplit) wgt[s][t] = m[s] * inv;
  }
  __syncthreads();
  int c = t;
  for (int row = 0; row < 64; ++row) {
    float h = 0.0f;
#pragma unroll
    for (int s = 0; s < 4; ++s) if (s < nsplit)
      h += pacc[(((size_t)s * 256 + g) * 64 + row) * 256 + c] * wgt[s][row];
    hbuf[((size_t)g * 64 + row) * 256 + c] = f2bf(h);
  }
}

// ---------------- K5: out[b][c][n] = b_proj[c] + sum_k h[b][n][k] Wp[c][k] ----------------
__global__ __launch_bounds__(256) void k_proj(const u16* __restrict__ hbuf, const u16* __restrict__ wp,
                                              const float* __restrict__ bproj, float* __restrict__ out) {
  __shared__ u16 Al[128][72];
  __shared__ u16 Bl[128][72];
  int n0 = blockIdx.x * 128;
  int c0 = blockIdx.y * 128;
  int b  = blockIdx.z;
  int tid = threadIdx.x;
  int lane = tid & 63, w = tid >> 6;
  int lo = lane & 15, hi = lane >> 4;
  int wm = w >> 1, wn = w & 1;
  f32x4 acc[4][4] = {};
  const u16* Ab = wp + (size_t)c0 * CDIM;
  const u16* Bb = hbuf + ((size_t)b * NTOK + n0) * CDIM;
  for (int kc = 0; kc < 256; kc += 64) {
    __syncthreads();
#pragma unroll
    for (int i = 0; i < 4; ++i) {
      int cid = i * 256 + tid;
      int row = cid >> 3, cc = cid & 7;
      *(uint4*)&Al[row][cc * 8] = *(const uint4*)(Ab + (size_t)row * CDIM + kc + cc * 8);
      *(uint4*)&Bl[row][cc * 8] = *(const uint4*)(Bb + (size_t)row * CDIM + kc + cc * 8);
    }
    __syncthreads();
#pragma unroll
    for (int kk = 0; kk < 2; ++kk) {
      bf16x8 af[4], bfr[4];
#pragma unroll
      for (int mi = 0; mi < 4; ++mi) af[mi]  = *(const bf16x8*)&Al[wm * 64 + mi * 16 + lo][kk * 32 + hi * 8];
#pragma unroll
      for (int ni = 0; ni < 4; ++ni) bfr[ni] = *(const bf16x8*)&Bl[wn * 64 + ni * 16 + lo][kk * 32 + hi * 8];
#pragma unroll
      for (int mi = 0; mi < 4; ++mi)
#pragma unroll
        for (int ni = 0; ni < 4; ++ni)
          acc[mi][ni] = __builtin_amdgcn_mfma_f32_16x16x32_bf16(af[mi], bfr[ni], acc[mi][ni], 0, 0, 0);
    }
  }
#pragma unroll
  for (int mi = 0; mi < 4; ++mi) {
    int cbase = c0 + wm * 64 + mi * 16 + hi * 4;
#pragma unroll
    for (int r = 0; r < 4; ++r) {
      float bias = bproj[cbase + r];
#pragma unroll
      for (int ni = 0; ni < 4; ++ni) {
        int n = n0 + wn * 64 + ni * 16 + lo;
        out[((size_t)b * CDIM + cbase + r) * NTOK + n] = acc[mi][ni][r] + bias;
      }
    }
  }
}

extern "C" void kernel_launch(void* const* d_in, const int* in_sizes, int n_in,
                              void* d_out, int out_size, void* d_ws, size_t ws_size,
                              hipStream_t stream) {
  const float* x     = (const float*)d_in[0];
  const int*   fg    = (const int*)d_in[1];
  const float* Wqkv  = (const float*)d_in[2];
  const float* Wproj = (const float*)d_in[3];
  const float* bproj = (const float*)d_in[4];
  float* out = (float*)d_out;
  char* ws = (char*)d_ws;
  // workspace layout (bytes); hbuf reuses xbf (dead after k_qkv).
  u16*   xbf  = (u16*)(ws);                    // 8388608 B (also hbuf)
  u16*   Qm   = (u16*)(ws + 8388608);          // 8388608
  u16*   Km   = (u16*)(ws + 16777216);         // 8388608
  u16*   Vt   = (u16*)(ws + 25165824);         // 8388608
  u16*   wq   = (u16*)(ws + 33554432);         // 393216
  u16*   wp   = (u16*)(ws + 33947648);         // 131072
  float* madd = (float*)(ws + 34078720);       // 65536  -> ends 34144256
  u16*   hbuf = xbf;

  const size_t base = 34144256;
  const size_t per_acc = (size_t)256 * 64 * 256 * 4;   // 16 MiB per split
  const size_t per_ml  = (size_t)256 * 64 * 8;         // 128 KiB per split
  int nsplit = 4, lsplit = 2;
  if (base + 4 * (per_acc + per_ml) > ws_size) { nsplit = 2; lsplit = 1; }
  if (base + 2 * (per_acc + per_ml) > ws_size) { nsplit = 1; lsplit = 0; }
  float*  pacc = (float*)(ws + base);
  float2* pml  = (float2*)(ws + base + (size_t)nsplit * per_acc);

  k_prep<<<1088, 256, 0, stream>>>(Wqkv, Wproj, fg, wq, wp, madd);
  k_transpose<<<dim3(64, 4, 4), 256, 0, stream>>>(x, xbf);
  k_qkv<<<dim3(32, 6, 4), 256, 0, stream>>>(xbf, wq, Qm, Km, Vt);
  k_attn<<<256 * nsplit, 256, 0, stream>>>(Qm, Km, Vt, madd, pacc, pml, lsplit);
  k_comb<<<256, 256, 0, stream>>>(pacc, pml, hbuf, nsplit);
  k_proj<<<dim3(32, 2, 4), 256, 0, stream>>>(hbuf, wp, bproj, out);
}